// Round 3
// baseline (502.894 us; speedup 1.0000x reference)
//
#include <hip/hip_runtime.h>
#include <hip/hip_bf16.h>
#include <cstdint>

#define N_NODES 100000
#define N_EDGES 1600000
#define F_IN    512
#define F_HID   128
#define F_OUT   40
#define F_OUT_PAD 48

// bucketed CSR build params
#define BSH    8                       // 256 nodes per bucket
#define NB     391                     // ceil(100000/256)
#define BEPT   8                       // edges per thread (bucket kernels)
#define BCHUNK 4096                    // 512 thr * 8 edges per block
#define GB     391                     // ceil(E / BCHUNK)
#define CONVB  140                     // conv blocks appended to bhist grid
#define FCAP   6144                    // k_fine LDS record capacity (avg 4092, std 64)
#define DBINS  64                      // degree-sort bins (deg clamped to 63)

typedef short v8s __attribute__((ext_vector_type(8)));
typedef float v4f __attribute__((ext_vector_type(4)));

__device__ __forceinline__ short f2bf(float f) {
    unsigned u = __float_as_uint(f);
    u += 0x7fffu + ((u >> 16) & 1u);
    return (short)(u >> 16);
}

__device__ __forceinline__ float bflo(unsigned u) { return __uint_as_float(u << 16); }
__device__ __forceinline__ float bfhi(unsigned u) { return __uint_as_float(u & 0xffff0000u); }

__device__ __forceinline__ v8s pack8(float4 a, float4 b) {
    v8s r;
    r[0] = f2bf(a.x); r[1] = f2bf(a.y); r[2] = f2bf(a.z); r[3] = f2bf(a.w);
    r[4] = f2bf(b.x); r[5] = f2bf(b.y); r[6] = f2bf(b.z); r[7] = f2bf(b.w);
    return r;
}

// async 16B global->LDS (direct-to-shared DMA; LDS dest = wave-uniform base + lane*16)
__device__ __forceinline__ void gload16(const void* g, void* l) {
    __builtin_amdgcn_global_load_lds(
        (const __attribute__((address_space(1))) void*)g,
        (__attribute__((address_space(3))) void*)l, 16, 0, 0);
}

// ---------------- bucketed CSR build ----------------

// A: bucket histogram (LDS-aggregated) + weight convert (independent blocks)
__global__ __launch_bounds__(512) void k_bhist(const int* __restrict__ dst,
                                               int* __restrict__ bcnt,
                                               const float* __restrict__ W1,
                                               short* __restrict__ WT1,
                                               const float* __restrict__ W2,
                                               short* __restrict__ WT2) {
    if (blockIdx.x >= GB) { // weight transpose+convert tail blocks
        int i = (blockIdx.x - GB) * 512 + threadIdx.x;
        if (i < F_IN * F_HID) {            // i = n*512 + k
            int n = i >> 9, k = i & 511;
            WT1[i] = f2bf(W1[k * F_HID + n]);
        } else {
            int j = i - F_IN * F_HID;      // j = n*128 + k
            if (j < F_OUT_PAD * F_HID) {
                int n = j >> 7, k = j & 127;
                WT2[j] = (n < F_OUT) ? f2bf(W2[k * F_OUT + n]) : (short)0;
            }
        }
        return;
    }
    __shared__ int lh[512];
    int tid = threadIdx.x;
    lh[tid] = 0;
    __syncthreads();
    long e0 = (long)blockIdx.x * BCHUNK;
#pragma unroll
    for (int i = 0; i < BEPT; i++) {
        long e = e0 + tid + i * 512;
        if (e < N_EDGES) atomicAdd(&lh[dst[e] >> BSH], 1);
    }
    __syncthreads();
    if (tid < NB && lh[tid]) atomicAdd(&bcnt[tid], lh[tid]);
}

// scan bucket counts -> bucket bases; seed bucket cursors
__global__ __launch_bounds__(512) void k_bscan(const int* __restrict__ bcnt,
                                               int* __restrict__ bbase,
                                               int* __restrict__ bcur) {
    __shared__ int sm[512];
    int tid = threadIdx.x;
    int v = (tid < NB) ? bcnt[tid] : 0;
    sm[tid] = v;
    __syncthreads();
    for (int off = 1; off < 512; off <<= 1) {
        int t = (tid >= off) ? sm[tid - off] : 0;
        __syncthreads();
        sm[tid] += t;
        __syncthreads();
    }
    if (tid < NB) {
        int ex = sm[tid] - v;
        bbase[tid] = ex;
        bcur[tid] = ex;
    }
    if (tid == 511) bbase[NB] = sm[511];
}

// B: reorder edges into bucket-major tmp.
// tmp record: (src | dstLow<<17, w_bits)  [src<2^17, dstLow<2^8]
__global__ __launch_bounds__(512) void k_bscatter(const int* __restrict__ src,
                                                  const int* __restrict__ dst,
                                                  const float* __restrict__ w,
                                                  int* __restrict__ bcur,
                                                  int2* __restrict__ tmp) {
    __shared__ int cntA[512];
    __shared__ int ofsA[512];
    __shared__ int lcur[512];
    __shared__ int gb[512];
    __shared__ __align__(16) int2 recBuf[BCHUNK];
    __shared__ unsigned short bkt[BCHUNK];
    int tid = threadIdx.x;
    long e0 = (long)blockIdx.x * BCHUNK;
    cntA[tid] = 0;
    __syncthreads();

    int dloc[BEPT];
#pragma unroll
    for (int i = 0; i < BEPT; i++) {
        long e = e0 + tid + i * 512;
        int d = (e < N_EDGES) ? dst[e] : -1;
        dloc[i] = d;
        if (d >= 0) atomicAdd(&cntA[d >> BSH], 1);
    }
    __syncthreads();

    int v = cntA[tid];
    ofsA[tid] = v;
    __syncthreads();
    for (int off = 1; off < 512; off <<= 1) {
        int t = (tid >= off) ? ofsA[tid - off] : 0;
        __syncthreads();
        ofsA[tid] += t;
        __syncthreads();
    }
    int excl = ofsA[tid] - v;
    ofsA[tid] = excl;
    lcur[tid] = excl;
    if (tid < NB && v > 0) gb[tid] = atomicAdd(&bcur[tid], v);
    __syncthreads();

#pragma unroll
    for (int i = 0; i < BEPT; i++) {
        int d = dloc[i];
        if (d >= 0) {
            long e = e0 + tid + i * 512;
            int j = d >> BSH;
            int slot = atomicAdd(&lcur[j], 1);
            recBuf[slot] = make_int2(src[e] | ((d & 255) << 17), __float_as_int(w[e]));
            bkt[slot] = (unsigned short)j;
        }
    }
    __syncthreads();

    long rem = N_EDGES - e0;
    int total = (rem < BCHUNK) ? (int)rem : BCHUNK;
    for (int s = tid; s < total; s += 512) {
        int j = bkt[s];
        tmp[gb[j] + (s - ofsA[j])] = recBuf[s];
    }
}

// C: per-bucket fine sort by node; emits rowptr/deg + degree histogram.
__global__ __launch_bounds__(256) void k_fine(const int2* __restrict__ tmp,
                                              const int* __restrict__ bbase,
                                              int2* __restrict__ rec,
                                              int* __restrict__ rowptr,
                                              int* __restrict__ deg,
                                              int* __restrict__ dcnt) {
    __shared__ int hist[256];
    __shared__ int ofs[256];
    __shared__ int cur[256];
    __shared__ int dh[DBINS];
    __shared__ __align__(16) int2 recOut[FCAP];
    int tid = threadIdx.x, b = blockIdx.x;
    int base = bbase[b];
    int cnt = bbase[b + 1] - base;

    hist[tid] = 0;
    if (tid < DBINS) dh[tid] = 0;
    __syncthreads();
    for (int i = tid; i < cnt; i += 256) {
        unsigned u = (unsigned)tmp[base + i].x;
        atomicAdd(&hist[u >> 17], 1);
    }
    __syncthreads();

    int v = hist[tid];
    ofs[tid] = v;
    __syncthreads();
    for (int off = 1; off < 256; off <<= 1) {
        int t = (tid >= off) ? ofs[tid - off] : 0;
        __syncthreads();
        ofs[tid] += t;
        __syncthreads();
    }
    int excl = ofs[tid] - v;
    ofs[tid] = excl;
    cur[tid] = excl;
    int node = (b << BSH) + tid;
    if (node < N_NODES) {
        rowptr[node] = base + excl;
        deg[node] = v;
        atomicAdd(&dh[v < DBINS ? v : DBINS - 1], 1);
    }
    __syncthreads();
    if (tid < DBINS && dh[tid]) atomicAdd(&dcnt[tid], dh[tid]);

    if (cnt <= FCAP) {
        for (int i = tid; i < cnt; i += 256) {
            int2 r = tmp[base + i];
            unsigned u = (unsigned)r.x;
            int slot = atomicAdd(&cur[u >> 17], 1);
            recOut[slot] = make_int2((int)(u & 0x1FFFFu), r.y);
        }
        __syncthreads();
        for (int i = tid; i < cnt; i += 256) rec[base + i] = recOut[i];
    } else { // statistically unreachable overflow fallback (still correct)
        for (int i = tid; i < cnt; i += 256) {
            int2 r = tmp[base + i];
            unsigned u = (unsigned)r.x;
            int slot = atomicAdd(&cur[u >> 17], 1);
            rec[base + slot] = make_int2((int)(u & 0x1FFFFu), r.y);
        }
    }
}

// D: scan degree bins -> cursors
__global__ __launch_bounds__(DBINS) void k_dscan(const int* __restrict__ dcnt,
                                                 int* __restrict__ dcur) {
    __shared__ int sm[DBINS];
    int tid = threadIdx.x;
    int v = dcnt[tid];
    sm[tid] = v;
    __syncthreads();
    for (int off = 1; off < DBINS; off <<= 1) {
        int t = (tid >= off) ? sm[tid - off] : 0;
        __syncthreads();
        sm[tid] += t;
        __syncthreads();
    }
    dcur[tid] = sm[tid] - v;
}

// E: counting-sort node ids by degree into nodeinfo = {node, rowptr, deg, 0}
__global__ __launch_bounds__(256) void k_dscatter(const int* __restrict__ rowptr,
                                                  const int* __restrict__ deg,
                                                  int* __restrict__ dcur,
                                                  int4* __restrict__ ninfo) {
    __shared__ int lh[DBINS];
    __shared__ int gbase[DBINS];
    int tid = threadIdx.x;
    if (tid < DBINS) lh[tid] = 0;
    __syncthreads();
    int node = blockIdx.x * 256 + tid;
    int d = 0, lpos = 0, st = 0, ct = 0;
    bool valid = node < N_NODES;
    if (valid) {
        st = rowptr[node];
        ct = deg[node];
        d = ct < DBINS ? ct : DBINS - 1;
        lpos = atomicAdd(&lh[d], 1);
    }
    __syncthreads();
    if (tid < DBINS && lh[tid]) gbase[tid] = atomicAdd(&dcur[tid], lh[tid]);
    __syncthreads();
    if (valid) ninfo[gbase[d] + lpos] = make_int4(node, st, ct, 0);
}

// ---------------- GEMM1 (LDS-staged): m1b = x @ W1 ----------------

__global__ __launch_bounds__(256) void k_gemm1(const float* __restrict__ x,
                                               const short* __restrict__ WT1,
                                               unsigned short* __restrict__ m1b) {
    __shared__ __align__(16) float aBuf[2][64 * 32];  // 2 x 8 KB
    __shared__ __align__(16) short bBuf[2][128 * 32]; // 2 x 8 KB
    int tid = threadIdx.x, w = tid >> 6, lane = tid & 63;
    int quad = lane >> 4, l16 = lane & 15;
    long rowBase = (long)blockIdx.x * 64;

    int ar = lane >> 3, ac = lane & 7; // A: 8 rows x 8 kblocks(16B=4 floats)
    int br = lane >> 2, bc = lane & 3; // B: 16 rows x 4 kblocks(16B=8 bf16)

    v4f acc[8];
#pragma unroll
    for (int t = 0; t < 8; t++) acc[t] = (v4f){0.f, 0.f, 0.f, 0.f};

    auto stage = [&](int kc, int buf) {
#pragma unroll
        for (int i = 0; i < 2; i++) {
            int rl = w * 16 + i * 8 + ar;
            long rg = rowBase + rl;
            if (rg > N_NODES - 1) rg = N_NODES - 1;
            const float* gp = x + rg * F_IN + kc * 32 + ((ac ^ (rl & 7)) << 2);
            gload16(gp, &aBuf[buf][(w * 16 + i * 8) * 32]);
        }
#pragma unroll
        for (int i = 0; i < 2; i++) {
            int n = w * 32 + i * 16 + br;
            const short* gp = WT1 + n * F_IN + kc * 32 + ((bc ^ ((n >> 1) & 3)) << 3);
            gload16(gp, &bBuf[buf][(w * 32 + i * 16) * 32]);
        }
    };

    stage(0, 0);
#pragma unroll
    for (int kc = 0; kc < 16; kc++) {
        __syncthreads();
        int buf = kc & 1;
        if (kc < 15) stage(kc + 1, buf ^ 1);
        int arow = w * 16 + l16;
        int p0 = (2 * quad) ^ (l16 & 7);
        float4 av0 = *(const float4*)&aBuf[buf][arow * 32 + p0 * 4];
        float4 av1 = *(const float4*)&aBuf[buf][arow * 32 + (p0 ^ 1) * 4];
        v8s af = pack8(av0, av1);
#pragma unroll
        for (int t = 0; t < 8; t++) {
            int n = t * 16 + l16;
            int p = quad ^ ((n >> 1) & 3);
            v8s bf = *(const v8s*)&bBuf[buf][n * 32 + p * 8];
            acc[t] = __builtin_amdgcn_mfma_f32_16x16x32_bf16(af, bf, acc[t], 0, 0, 0);
        }
    }

#pragma unroll
    for (int t = 0; t < 8; t++)
#pragma unroll
        for (int r = 0; r < 4; r++) {
            long row = rowBase + w * 16 + quad * 4 + r;
            if (row < N_NODES)
                m1b[row * F_HID + t * 16 + l16] = (unsigned short)f2bf(acc[t][r]);
        }
}

// ---------------- layer-1 aggregation: wave/node (deg-sorted), QUARTER-wave
// per edge. 16 lanes x 16 B (uint4 = 8 bf16) cover the 256 B row; one
// dwordx4 gather covers 4 edges. Cross-quarter shfl reduction.

__global__ void k_agg1(const int2* __restrict__ rec, const int4* __restrict__ ninfo,
                       const uint4* __restrict__ m1v, const float* __restrict__ b1,
                       uint4* __restrict__ h4) {
    int gid = blockIdx.x * 4 + (threadIdx.x >> 6);
    int lane = threadIdx.x & 63;
    if (gid >= N_NODES) return;
    int4 ni = ninfo[gid];
    int node = ni.x, start = ni.y, cnt = ni.z;
    int q = lane >> 4, l16 = lane & 15;

    float a0 = 0.f, a1 = 0.f, a2 = 0.f, a3 = 0.f;
    float a4 = 0.f, a5 = 0.f, a6 = 0.f, a7 = 0.f;
    float c0 = 0.f, c1 = 0.f, c2 = 0.f, c3 = 0.f;
    float c4 = 0.f, c5 = 0.f, c6 = 0.f, c7 = 0.f;

    int nmain = cnt >> 3; // 8 edges per iter (2 per quarter)
    int eb = start + q;
    for (int k = 0; k < nmain; k++) {
        int e = eb + (k << 3);
        int2 r0 = rec[e];
        int2 r1 = rec[e + 4];
        uint4 g0 = m1v[(long)r0.x * 16 + l16];
        uint4 g1 = m1v[(long)r1.x * 16 + l16];
        float w0 = __int_as_float(r0.y), w1 = __int_as_float(r1.y);
        a0 = fmaf(w0, bflo(g0.x), a0); a1 = fmaf(w0, bfhi(g0.x), a1);
        a2 = fmaf(w0, bflo(g0.y), a2); a3 = fmaf(w0, bfhi(g0.y), a3);
        a4 = fmaf(w0, bflo(g0.z), a4); a5 = fmaf(w0, bfhi(g0.z), a5);
        a6 = fmaf(w0, bflo(g0.w), a6); a7 = fmaf(w0, bfhi(g0.w), a7);
        c0 = fmaf(w1, bflo(g1.x), c0); c1 = fmaf(w1, bfhi(g1.x), c1);
        c2 = fmaf(w1, bflo(g1.y), c2); c3 = fmaf(w1, bfhi(g1.y), c3);
        c4 = fmaf(w1, bflo(g1.z), c4); c5 = fmaf(w1, bfhi(g1.z), c5);
        c6 = fmaf(w1, bflo(g1.w), c6); c7 = fmaf(w1, bfhi(g1.w), c7);
    }
    for (int e = start + (nmain << 3) + q; e < start + cnt; e += 4) {
        int2 r = rec[e];
        uint4 g = m1v[(long)r.x * 16 + l16];
        float w = __int_as_float(r.y);
        a0 = fmaf(w, bflo(g.x), a0); a1 = fmaf(w, bfhi(g.x), a1);
        a2 = fmaf(w, bflo(g.y), a2); a3 = fmaf(w, bfhi(g.y), a3);
        a4 = fmaf(w, bflo(g.z), a4); a5 = fmaf(w, bfhi(g.z), a5);
        a6 = fmaf(w, bflo(g.w), a6); a7 = fmaf(w, bfhi(g.w), a7);
    }
    a0 += c0; a1 += c1; a2 += c2; a3 += c3;
    a4 += c4; a5 += c5; a6 += c6; a7 += c7;
    a0 += __shfl_xor(a0, 16); a0 += __shfl_xor(a0, 32);
    a1 += __shfl_xor(a1, 16); a1 += __shfl_xor(a1, 32);
    a2 += __shfl_xor(a2, 16); a2 += __shfl_xor(a2, 32);
    a3 += __shfl_xor(a3, 16); a3 += __shfl_xor(a3, 32);
    a4 += __shfl_xor(a4, 16); a4 += __shfl_xor(a4, 32);
    a5 += __shfl_xor(a5, 16); a5 += __shfl_xor(a5, 32);
    a6 += __shfl_xor(a6, 16); a6 += __shfl_xor(a6, 32);
    a7 += __shfl_xor(a7, 16); a7 += __shfl_xor(a7, 32);
    if (q == 0) {
        const float4* b4 = (const float4*)b1;
        float4 bv0 = b4[2 * l16], bv1 = b4[2 * l16 + 1];
        a0 = fmaxf(a0 + bv0.x, 0.f); a1 = fmaxf(a1 + bv0.y, 0.f);
        a2 = fmaxf(a2 + bv0.z, 0.f); a3 = fmaxf(a3 + bv0.w, 0.f);
        a4 = fmaxf(a4 + bv1.x, 0.f); a5 = fmaxf(a5 + bv1.y, 0.f);
        a6 = fmaxf(a6 + bv1.z, 0.f); a7 = fmaxf(a7 + bv1.w, 0.f);
        uint4 o;
        o.x = (unsigned)(unsigned short)f2bf(a0) | ((unsigned)(unsigned short)f2bf(a1) << 16);
        o.y = (unsigned)(unsigned short)f2bf(a2) | ((unsigned)(unsigned short)f2bf(a3) << 16);
        o.z = (unsigned)(unsigned short)f2bf(a4) | ((unsigned)(unsigned short)f2bf(a5) << 16);
        o.w = (unsigned)(unsigned short)f2bf(a6) | ((unsigned)(unsigned short)f2bf(a7) << 16);
        h4[(long)node * 16 + l16] = o;
    }
}

// ---------------- GEMM2: m2b[100000,64] (bf16) = h @ W2; cols 40..63 zero ----------

__global__ __launch_bounds__(256) void k_gemm2(const unsigned short* __restrict__ h,
                                               const short* __restrict__ WT2,
                                               unsigned short* __restrict__ m2b) {
    int wave = threadIdx.x >> 6, lane = threadIdx.x & 63;
    int quad = lane >> 4, l16 = lane & 15;
    long rowBase = ((long)blockIdx.x * 4 + wave) * 16;
    if (rowBase >= N_NODES) return;

    v4f acc[3];
#pragma unroll
    for (int t = 0; t < 3; t++) acc[t] = (v4f){0.f, 0.f, 0.f, 0.f};

    const short* arow = (const short*)h + (rowBase + l16) * (long)F_HID + quad * 8;
    const short* brow = WT2 + l16 * F_HID + quad * 8;
#pragma unroll
    for (int k0 = 0; k0 < F_HID; k0 += 32) {
        v8s af = *reinterpret_cast<const v8s*>(arow + k0);
#pragma unroll
        for (int t = 0; t < 3; t++) {
            v8s bf = *reinterpret_cast<const v8s*>(brow + t * 16 * F_HID + k0);
            acc[t] = __builtin_amdgcn_mfma_f32_16x16x32_bf16(af, bf, acc[t], 0, 0, 0);
        }
    }
#pragma unroll
    for (int r = 0; r < 4; r++) {
        long row = rowBase + quad * 4 + r;
#pragma unroll
        for (int t = 0; t < 3; t++)
            m2b[row * 64 + t * 16 + l16] = (unsigned short)f2bf(acc[t][r]);
        m2b[row * 64 + 48 + l16] = 0;
    }
}

// ---------------- layer-2 aggregation + bias + log_softmax ------------------
// EIGHTH-wave per edge: 8 lanes x 16 B (uint4 = 8 bf16) cover the 128 B row;
// one dwordx4 gather covers 8 edges. Cross-oct shfl reduction; softmax over
// 8-lane groups; 2 x float4 output stores per useful lane.

__global__ void k_agg2(const int2* __restrict__ rec, const int4* __restrict__ ninfo,
                       const uint4* __restrict__ m2v, const float* __restrict__ b2,
                       float* __restrict__ out) {
    int gid = blockIdx.x * 4 + (threadIdx.x >> 6);
    int lane = threadIdx.x & 63;
    if (gid >= N_NODES) return;
    int4 ni = ninfo[gid];
    int node = ni.x, start = ni.y, cnt = ni.z;
    int oc = lane >> 3, l8 = lane & 7;

    float a0 = 0.f, a1 = 0.f, a2 = 0.f, a3 = 0.f;
    float a4 = 0.f, a5 = 0.f, a6 = 0.f, a7 = 0.f;

    int nmain = cnt >> 3; // 8 edges per iter (1 per oct)
    int eb = start + oc;
    for (int k = 0; k < nmain; k++) {
        int2 r = rec[eb + (k << 3)];
        uint4 g = m2v[(long)r.x * 8 + l8];
        float w = __int_as_float(r.y);
        a0 = fmaf(w, bflo(g.x), a0); a1 = fmaf(w, bfhi(g.x), a1);
        a2 = fmaf(w, bflo(g.y), a2); a3 = fmaf(w, bfhi(g.y), a3);
        a4 = fmaf(w, bflo(g.z), a4); a5 = fmaf(w, bfhi(g.z), a5);
        a6 = fmaf(w, bflo(g.w), a6); a7 = fmaf(w, bfhi(g.w), a7);
    }
    {
        int e = start + (nmain << 3) + oc;
        if (e < start + cnt) {
            int2 r = rec[e];
            uint4 g = m2v[(long)r.x * 8 + l8];
            float w = __int_as_float(r.y);
            a0 = fmaf(w, bflo(g.x), a0); a1 = fmaf(w, bfhi(g.x), a1);
            a2 = fmaf(w, bflo(g.y), a2); a3 = fmaf(w, bfhi(g.y), a3);
            a4 = fmaf(w, bflo(g.z), a4); a5 = fmaf(w, bfhi(g.z), a5);
            a6 = fmaf(w, bflo(g.w), a6); a7 = fmaf(w, bfhi(g.w), a7);
        }
    }
    // reduce across octs: xor 8,16,32
#pragma unroll
    for (int off = 8; off < 64; off <<= 1) {
        a0 += __shfl_xor(a0, off); a1 += __shfl_xor(a1, off);
        a2 += __shfl_xor(a2, off); a3 += __shfl_xor(a3, off);
        a4 += __shfl_xor(a4, off); a5 += __shfl_xor(a5, off);
        a6 += __shfl_xor(a6, off); a7 += __shfl_xor(a7, off);
    }

    const float NEG = -3.4e38f;
    float v0 = NEG, v1 = NEG, v2 = NEG, v3 = NEG;
    float v4 = NEG, v5 = NEG, v6 = NEG, v7 = NEG;
    if (l8 < 5) { // feats 8*l8 .. +7 all < 40
        const float4* b4 = (const float4*)b2;
        float4 bv0 = b4[2 * l8], bv1 = b4[2 * l8 + 1];
        v0 = a0 + bv0.x; v1 = a1 + bv0.y; v2 = a2 + bv0.z; v3 = a3 + bv0.w;
        v4 = a4 + bv1.x; v5 = a5 + bv1.y; v6 = a6 + bv1.z; v7 = a7 + bv1.w;
    }
    float m = fmaxf(fmaxf(fmaxf(v0, v1), fmaxf(v2, v3)),
                    fmaxf(fmaxf(v4, v5), fmaxf(v6, v7)));
#pragma unroll
    for (int off = 1; off < 8; off <<= 1) m = fmaxf(m, __shfl_xor(m, off));
    float s = 0.f;
    if (l8 < 5)
        s = __expf(v0 - m) + __expf(v1 - m) + __expf(v2 - m) + __expf(v3 - m) +
            __expf(v4 - m) + __expf(v5 - m) + __expf(v6 - m) + __expf(v7 - m);
#pragma unroll
    for (int off = 1; off < 8; off <<= 1) s += __shfl_xor(s, off);
    if (oc == 0 && l8 < 5) {
        float ls = m + __logf(s);
        float4* op = (float4*)(out + (long)node * F_OUT);
        float4 o0, o1;
        o0.x = v0 - ls; o0.y = v1 - ls; o0.z = v2 - ls; o0.w = v3 - ls;
        o1.x = v4 - ls; o1.y = v5 - ls; o1.z = v6 - ls; o1.w = v7 - ls;
        op[2 * l8] = o0;
        op[2 * l8 + 1] = o1;
    }
}

// ---------------- launch ----------------

extern "C" void kernel_launch(void* const* d_in, const int* in_sizes, int n_in,
                              void* d_out, int out_size, void* d_ws, size_t ws_size,
                              hipStream_t stream) {
    const float* x  = (const float*)d_in[0];
    const int* ei   = (const int*)d_in[1]; // [2, E]: src then dst (int32)
    const int* src  = ei;
    const int* dst  = ei + N_EDGES;
    const float* ew = (const float*)d_in[2];
    const float* W1 = (const float*)d_in[3];
    const float* b1 = (const float*)d_in[4];
    const float* W2 = (const float*)d_in[5];
    const float* b2 = (const float*)d_in[6];
    float* out = (float*)d_out;

    char* ws = (char*)d_ws;
    size_t off = 0;
    auto alloc = [&](size_t bytes) {
        void* p = ws + off;
        off += (bytes + 255) & ~(size_t)255;
        return p;
    };
    unsigned short* m1b  = (unsigned short*)alloc((size_t)N_NODES * F_HID * 2); // 25.6 MB
    unsigned int*   h    = (unsigned int*)alloc((size_t)N_NODES * F_HID * 2);   // 25.6 MB
    unsigned short* m2b  = (unsigned short*)alloc((size_t)N_NODES * 64 * 2);    // 12.8 MB
    int2*           rec  = (int2*)alloc((size_t)N_EDGES * 8);                   // 12.8 MB
    int*          rowptr = (int*)alloc((size_t)N_NODES * 4);
    int*          deg    = (int*)alloc((size_t)N_NODES * 4);
    int4*         ninfo  = (int4*)alloc((size_t)N_NODES * 16);                  // 1.6 MB
    int*          ctrl   = (int*)alloc(1024 * 4); // bCnt[512] | dcnt[64] | dcur[64]
    int*          bBase  = (int*)alloc(512 * 4);
    int*          bCur   = (int*)alloc(512 * 4);
    short*        WT1    = (short*)alloc((size_t)F_HID * F_IN * 2);
    short*        WT2    = (short*)alloc((size_t)F_OUT_PAD * F_HID * 2);

    int* bCnt = ctrl;
    int* dcnt = ctrl + 512;
    int* dcur = ctrl + 576;

    // tmp (bucket-major edge records) aliases m2b: both 12.8 MB; tmp is dead
    // before k_gemm2 writes m2b.
    int2* tmp = (int2*)m2b;

    hipMemsetAsync(ctrl, 0, 576 * 4, stream); // zeros bCnt + dcnt

    k_bhist<<<GB + CONVB, 512, 0, stream>>>(dst, bCnt, W1, WT1, W2, WT2);
    k_bscan<<<1, 512, 0, stream>>>(bCnt, bBase, bCur);
    k_bscatter<<<GB, 512, 0, stream>>>(src, dst, ew, bCur, tmp);
    k_fine<<<NB, 256, 0, stream>>>(tmp, bBase, rec, rowptr, deg, dcnt);
    k_dscan<<<1, DBINS, 0, stream>>>(dcnt, dcur);
    k_dscatter<<<(N_NODES + 255) / 256, 256, 0, stream>>>(rowptr, deg, dcur, ninfo);

    k_gemm1<<<(N_NODES + 63) / 64, 256, 0, stream>>>(x, WT1, m1b);
    k_agg1<<<(N_NODES + 3) / 4, 256, 0, stream>>>(rec, ninfo, (const uint4*)m1b,
                                                  b1, (uint4*)h);
    k_gemm2<<<(N_NODES + 63) / 64, 256, 0, stream>>>((const unsigned short*)h, WT2, m2b);
    k_agg2<<<(N_NODES + 3) / 4, 256, 0, stream>>>(rec, ninfo, (const uint4*)m2b,
                                                  b2, out);
}

// Round 4
// 491.042 us; speedup vs baseline: 1.0241x; 1.0241x over previous
//
#include <hip/hip_runtime.h>
#include <hip/hip_bf16.h>
#include <cstdint>

#define N_NODES 100000
#define N_EDGES 1600000
#define F_IN    512
#define F_HID   128
#define F_OUT   40
#define F_OUT_PAD 48

// bucketed CSR build params
#define BSH    8                       // 256 nodes per bucket
#define NB     391                     // ceil(100000/256)
#define BEPT   8                       // edges per thread (bucket kernels)
#define BCHUNK 4096                    // 512 thr * 8 edges per block
#define GB     391                     // ceil(E / BCHUNK)
#define CONVB  140                     // conv blocks appended to bhist grid
#define FCAP   6144                    // k_fine LDS record capacity (avg 4092, std 64)

typedef short v8s __attribute__((ext_vector_type(8)));
typedef float v4f __attribute__((ext_vector_type(4)));

__device__ __forceinline__ short f2bf(float f) {
    unsigned u = __float_as_uint(f);
    u += 0x7fffu + ((u >> 16) & 1u);
    return (short)(u >> 16);
}

__device__ __forceinline__ float bflo(unsigned u) { return __uint_as_float(u << 16); }
__device__ __forceinline__ float bfhi(unsigned u) { return __uint_as_float(u & 0xffff0000u); }

__device__ __forceinline__ v8s pack8(float4 a, float4 b) {
    v8s r;
    r[0] = f2bf(a.x); r[1] = f2bf(a.y); r[2] = f2bf(a.z); r[3] = f2bf(a.w);
    r[4] = f2bf(b.x); r[5] = f2bf(b.y); r[6] = f2bf(b.z); r[7] = f2bf(b.w);
    return r;
}

// async 16B global->LDS (direct-to-shared DMA; LDS dest = wave-uniform base + lane*16)
__device__ __forceinline__ void gload16(const void* g, void* l) {
    __builtin_amdgcn_global_load_lds(
        (const __attribute__((address_space(1))) void*)g,
        (__attribute__((address_space(3))) void*)l, 16, 0, 0);
}

// ---------------- bucketed CSR build ----------------

// A: bucket histogram (LDS-aggregated) + weight convert (independent blocks)
__global__ __launch_bounds__(512) void k_bhist(const int* __restrict__ dst,
                                               int* __restrict__ bcnt,
                                               const float* __restrict__ W1,
                                               short* __restrict__ WT1,
                                               const float* __restrict__ W2,
                                               short* __restrict__ WT2) {
    if (blockIdx.x >= GB) { // weight transpose+convert tail blocks
        int i = (blockIdx.x - GB) * 512 + threadIdx.x;
        if (i < F_IN * F_HID) {            // i = n*512 + k
            int n = i >> 9, k = i & 511;
            WT1[i] = f2bf(W1[k * F_HID + n]);
        } else {
            int j = i - F_IN * F_HID;      // j = n*128 + k
            if (j < F_OUT_PAD * F_HID) {
                int n = j >> 7, k = j & 127;
                WT2[j] = (n < F_OUT) ? f2bf(W2[k * F_OUT + n]) : (short)0;
            }
        }
        return;
    }
    __shared__ int lh[512];
    int tid = threadIdx.x;
    lh[tid] = 0;
    __syncthreads();
    long e0 = (long)blockIdx.x * BCHUNK;
#pragma unroll
    for (int i = 0; i < BEPT; i++) {
        long e = e0 + tid + i * 512;
        if (e < N_EDGES) atomicAdd(&lh[dst[e] >> BSH], 1);
    }
    __syncthreads();
    if (tid < NB && lh[tid]) atomicAdd(&bcnt[tid], lh[tid]);
}

// scan bucket counts -> bucket bases; seed bucket cursors
__global__ __launch_bounds__(512) void k_bscan(const int* __restrict__ bcnt,
                                               int* __restrict__ bbase,
                                               int* __restrict__ bcur) {
    __shared__ int sm[512];
    int tid = threadIdx.x;
    int v = (tid < NB) ? bcnt[tid] : 0;
    sm[tid] = v;
    __syncthreads();
    for (int off = 1; off < 512; off <<= 1) {
        int t = (tid >= off) ? sm[tid - off] : 0;
        __syncthreads();
        sm[tid] += t;
        __syncthreads();
    }
    if (tid < NB) {
        int ex = sm[tid] - v;
        bbase[tid] = ex;
        bcur[tid] = ex;
    }
    if (tid == 511) bbase[NB] = sm[511];
}

// B: reorder edges into bucket-major tmp.
// tmp record: (src | dstLow<<17, w_bits)  [src<2^17, dstLow<2^8]
__global__ __launch_bounds__(512) void k_bscatter(const int* __restrict__ src,
                                                  const int* __restrict__ dst,
                                                  const float* __restrict__ w,
                                                  int* __restrict__ bcur,
                                                  int2* __restrict__ tmp) {
    __shared__ int cntA[512];
    __shared__ int ofsA[512];
    __shared__ int lcur[512];
    __shared__ int gb[512];
    __shared__ __align__(16) int2 recBuf[BCHUNK];
    __shared__ unsigned short bkt[BCHUNK];
    int tid = threadIdx.x;
    long e0 = (long)blockIdx.x * BCHUNK;
    cntA[tid] = 0;
    __syncthreads();

    int dloc[BEPT];
#pragma unroll
    for (int i = 0; i < BEPT; i++) {
        long e = e0 + tid + i * 512;
        int d = (e < N_EDGES) ? dst[e] : -1;
        dloc[i] = d;
        if (d >= 0) atomicAdd(&cntA[d >> BSH], 1);
    }
    __syncthreads();

    int v = cntA[tid];
    ofsA[tid] = v;
    __syncthreads();
    for (int off = 1; off < 512; off <<= 1) {
        int t = (tid >= off) ? ofsA[tid - off] : 0;
        __syncthreads();
        ofsA[tid] += t;
        __syncthreads();
    }
    int excl = ofsA[tid] - v;
    ofsA[tid] = excl;
    lcur[tid] = excl;
    if (tid < NB && v > 0) gb[tid] = atomicAdd(&bcur[tid], v);
    __syncthreads();

#pragma unroll
    for (int i = 0; i < BEPT; i++) {
        int d = dloc[i];
        if (d >= 0) {
            long e = e0 + tid + i * 512;
            int j = d >> BSH;
            int slot = atomicAdd(&lcur[j], 1);
            recBuf[slot] = make_int2(src[e] | ((d & 255) << 17), __float_as_int(w[e]));
            bkt[slot] = (unsigned short)j;
        }
    }
    __syncthreads();

    long rem = N_EDGES - e0;
    int total = (rem < BCHUNK) ? (int)rem : BCHUNK;
    for (int s = tid; s < total; s += 512) {
        int j = bkt[s];
        tmp[gb[j] + (s - ofsA[j])] = recBuf[s];
    }
}

// C: per-bucket fine sort by node; emits rowptr/deg and writes rec coalesced.
__global__ __launch_bounds__(256) void k_fine(const int2* __restrict__ tmp,
                                              const int* __restrict__ bbase,
                                              int2* __restrict__ rec,
                                              int* __restrict__ rowptr,
                                              int* __restrict__ deg) {
    __shared__ int hist[256];
    __shared__ int ofs[256];
    __shared__ int cur[256];
    __shared__ __align__(16) int2 recOut[FCAP];
    int tid = threadIdx.x, b = blockIdx.x;
    int base = bbase[b];
    int cnt = bbase[b + 1] - base;

    hist[tid] = 0;
    __syncthreads();
    for (int i = tid; i < cnt; i += 256) {
        unsigned u = (unsigned)tmp[base + i].x;
        atomicAdd(&hist[u >> 17], 1);
    }
    __syncthreads();

    int v = hist[tid];
    ofs[tid] = v;
    __syncthreads();
    for (int off = 1; off < 256; off <<= 1) {
        int t = (tid >= off) ? ofs[tid - off] : 0;
        __syncthreads();
        ofs[tid] += t;
        __syncthreads();
    }
    int excl = ofs[tid] - v;
    ofs[tid] = excl;
    cur[tid] = excl;
    int node = (b << BSH) + tid;
    if (node < N_NODES) {
        rowptr[node] = base + excl;
        deg[node] = v;
    }
    __syncthreads();

    if (cnt <= FCAP) {
        for (int i = tid; i < cnt; i += 256) {
            int2 r = tmp[base + i];
            unsigned u = (unsigned)r.x;
            int slot = atomicAdd(&cur[u >> 17], 1);
            recOut[slot] = make_int2((int)(u & 0x1FFFFu), r.y);
        }
        __syncthreads();
        for (int i = tid; i < cnt; i += 256) rec[base + i] = recOut[i];
    } else { // statistically unreachable overflow fallback (still correct)
        for (int i = tid; i < cnt; i += 256) {
            int2 r = tmp[base + i];
            unsigned u = (unsigned)r.x;
            int slot = atomicAdd(&cur[u >> 17], 1);
            rec[base + slot] = make_int2((int)(u & 0x1FFFFu), r.y);
        }
    }
}

// ---------------- GEMM1 (LDS-staged): m1b = x @ W1 ----------------

__global__ __launch_bounds__(256) void k_gemm1(const float* __restrict__ x,
                                               const short* __restrict__ WT1,
                                               unsigned short* __restrict__ m1b) {
    __shared__ __align__(16) float aBuf[2][64 * 32];  // 2 x 8 KB
    __shared__ __align__(16) short bBuf[2][128 * 32]; // 2 x 8 KB
    int tid = threadIdx.x, w = tid >> 6, lane = tid & 63;
    int quad = lane >> 4, l16 = lane & 15;
    long rowBase = (long)blockIdx.x * 64;

    int ar = lane >> 3, ac = lane & 7; // A: 8 rows x 8 kblocks(16B=4 floats)
    int br = lane >> 2, bc = lane & 3; // B: 16 rows x 4 kblocks(16B=8 bf16)

    v4f acc[8];
#pragma unroll
    for (int t = 0; t < 8; t++) acc[t] = (v4f){0.f, 0.f, 0.f, 0.f};

    auto stage = [&](int kc, int buf) {
#pragma unroll
        for (int i = 0; i < 2; i++) {
            int rl = w * 16 + i * 8 + ar;
            long rg = rowBase + rl;
            if (rg > N_NODES - 1) rg = N_NODES - 1;
            const float* gp = x + rg * F_IN + kc * 32 + ((ac ^ (rl & 7)) << 2);
            gload16(gp, &aBuf[buf][(w * 16 + i * 8) * 32]);
        }
#pragma unroll
        for (int i = 0; i < 2; i++) {
            int n = w * 32 + i * 16 + br;
            const short* gp = WT1 + n * F_IN + kc * 32 + ((bc ^ ((n >> 1) & 3)) << 3);
            gload16(gp, &bBuf[buf][(w * 32 + i * 16) * 32]);
        }
    };

    stage(0, 0);
#pragma unroll
    for (int kc = 0; kc < 16; kc++) {
        __syncthreads();
        int buf = kc & 1;
        if (kc < 15) stage(kc + 1, buf ^ 1);
        int arow = w * 16 + l16;
        int p0 = (2 * quad) ^ (l16 & 7);
        float4 av0 = *(const float4*)&aBuf[buf][arow * 32 + p0 * 4];
        float4 av1 = *(const float4*)&aBuf[buf][arow * 32 + (p0 ^ 1) * 4];
        v8s af = pack8(av0, av1);
#pragma unroll
        for (int t = 0; t < 8; t++) {
            int n = t * 16 + l16;
            int p = quad ^ ((n >> 1) & 3);
            v8s bf = *(const v8s*)&bBuf[buf][n * 32 + p * 8];
            acc[t] = __builtin_amdgcn_mfma_f32_16x16x32_bf16(af, bf, acc[t], 0, 0, 0);
        }
    }

#pragma unroll
    for (int t = 0; t < 8; t++)
#pragma unroll
        for (int r = 0; r < 4; r++) {
            long row = rowBase + w * 16 + quad * 4 + r;
            if (row < N_NODES)
                m1b[row * F_HID + t * 16 + l16] = (unsigned short)f2bf(acc[t][r]);
        }
}

// ---------------- FUSED layer-1 aggregation + ReLU + GEMM2 ------------------
// Wave handles 16 consecutive nodes. Per node: quarter-wave gather of m1b
// rows (16 lanes x 16 B), main loop issues 4 independent gathers (16 edges)
// before consuming. h row (bf16-packed, post-ReLU) goes to a swizzled LDS
// tile; then 12 MFMAs apply W2 and write m2b[.,64] directly (h never hits
// HBM: saves 51.2 MB round trip + a dispatch).

__global__ __launch_bounds__(256) void k_ag(const int2* __restrict__ rec,
                                            const int* __restrict__ rowptr,
                                            const int* __restrict__ deg,
                                            const uint4* __restrict__ m1v,
                                            const float* __restrict__ b1,
                                            const short* __restrict__ WT2,
                                            unsigned short* __restrict__ m2b) {
    __shared__ uint4 ht[4][16][16]; // [wave][node16][feat-slice] (slice swizzled)
    int tid = threadIdx.x, w = tid >> 6, lane = tid & 63;
    int q = lane >> 4, l16 = lane & 15;
    int gBase = (blockIdx.x * 4 + w) * 16; // this wave's 16 nodes

    // prefetch rowptr/deg for the 16 nodes (held in lanes 0-15, shfl-broadcast)
    int idx = gBase + l16;
    int rp = 0, dg = 0;
    if (idx < N_NODES) { rp = rowptr[idx]; dg = deg[idx]; }
    const float4* b4 = (const float4*)b1;
    float4 bv0 = b4[2 * l16], bv1 = b4[2 * l16 + 1];

    for (int i = 0; i < 16; i++) {
        int start = __shfl(rp, i);
        int cnt = __shfl(dg, i);
        float a0 = 0.f, a1 = 0.f, a2 = 0.f, a3 = 0.f;
        float a4 = 0.f, a5 = 0.f, a6 = 0.f, a7 = 0.f;
        int e = start + q;
        int n16 = cnt >> 4; // 16-edge batches: 4 gathers in flight
        for (int k = 0; k < n16; k++) {
            int2 r0 = rec[e];
            int2 r1 = rec[e + 4];
            int2 r2 = rec[e + 8];
            int2 r3 = rec[e + 12];
            uint4 g0 = m1v[(long)r0.x * 16 + l16];
            uint4 g1 = m1v[(long)r1.x * 16 + l16];
            uint4 g2 = m1v[(long)r2.x * 16 + l16];
            uint4 g3 = m1v[(long)r3.x * 16 + l16];
            float w0 = __int_as_float(r0.y), w1 = __int_as_float(r1.y);
            float w2 = __int_as_float(r2.y), w3 = __int_as_float(r3.y);
            a0 = fmaf(w0, bflo(g0.x), a0); a1 = fmaf(w0, bfhi(g0.x), a1);
            a2 = fmaf(w0, bflo(g0.y), a2); a3 = fmaf(w0, bfhi(g0.y), a3);
            a4 = fmaf(w0, bflo(g0.z), a4); a5 = fmaf(w0, bfhi(g0.z), a5);
            a6 = fmaf(w0, bflo(g0.w), a6); a7 = fmaf(w0, bfhi(g0.w), a7);
            a0 = fmaf(w1, bflo(g1.x), a0); a1 = fmaf(w1, bfhi(g1.x), a1);
            a2 = fmaf(w1, bflo(g1.y), a2); a3 = fmaf(w1, bfhi(g1.y), a3);
            a4 = fmaf(w1, bflo(g1.z), a4); a5 = fmaf(w1, bfhi(g1.z), a5);
            a6 = fmaf(w1, bflo(g1.w), a6); a7 = fmaf(w1, bfhi(g1.w), a7);
            a0 = fmaf(w2, bflo(g2.x), a0); a1 = fmaf(w2, bfhi(g2.x), a1);
            a2 = fmaf(w2, bflo(g2.y), a2); a3 = fmaf(w2, bfhi(g2.y), a3);
            a4 = fmaf(w2, bflo(g2.z), a4); a5 = fmaf(w2, bfhi(g2.z), a5);
            a6 = fmaf(w2, bflo(g2.w), a6); a7 = fmaf(w2, bfhi(g2.w), a7);
            a0 = fmaf(w3, bflo(g3.x), a0); a1 = fmaf(w3, bfhi(g3.x), a1);
            a2 = fmaf(w3, bflo(g3.y), a2); a3 = fmaf(w3, bfhi(g3.y), a3);
            a4 = fmaf(w3, bflo(g3.z), a4); a5 = fmaf(w3, bfhi(g3.z), a5);
            a6 = fmaf(w3, bflo(g3.w), a6); a7 = fmaf(w3, bfhi(g3.w), a7);
            e += 16;
        }
        if (cnt & 8) { // 8-edge batch: 2 gathers in flight
            int2 r0 = rec[e];
            int2 r1 = rec[e + 4];
            uint4 g0 = m1v[(long)r0.x * 16 + l16];
            uint4 g1 = m1v[(long)r1.x * 16 + l16];
            float w0 = __int_as_float(r0.y), w1 = __int_as_float(r1.y);
            a0 = fmaf(w0, bflo(g0.x), a0); a1 = fmaf(w0, bfhi(g0.x), a1);
            a2 = fmaf(w0, bflo(g0.y), a2); a3 = fmaf(w0, bfhi(g0.y), a3);
            a4 = fmaf(w0, bflo(g0.z), a4); a5 = fmaf(w0, bfhi(g0.z), a5);
            a6 = fmaf(w0, bflo(g0.w), a6); a7 = fmaf(w0, bfhi(g0.w), a7);
            a0 = fmaf(w1, bflo(g1.x), a0); a1 = fmaf(w1, bfhi(g1.x), a1);
            a2 = fmaf(w1, bflo(g1.y), a2); a3 = fmaf(w1, bfhi(g1.y), a3);
            a4 = fmaf(w1, bflo(g1.z), a4); a5 = fmaf(w1, bfhi(g1.z), a5);
            a6 = fmaf(w1, bflo(g1.w), a6); a7 = fmaf(w1, bfhi(g1.w), a7);
            e += 8;
        }
        for (int t = e; t < start + cnt; t += 4) { // <8 leftover, quarter-strided
            int2 r = rec[t];
            uint4 g = m1v[(long)r.x * 16 + l16];
            float ww = __int_as_float(r.y);
            a0 = fmaf(ww, bflo(g.x), a0); a1 = fmaf(ww, bfhi(g.x), a1);
            a2 = fmaf(ww, bflo(g.y), a2); a3 = fmaf(ww, bfhi(g.y), a3);
            a4 = fmaf(ww, bflo(g.z), a4); a5 = fmaf(ww, bfhi(g.z), a5);
            a6 = fmaf(ww, bflo(g.w), a6); a7 = fmaf(ww, bfhi(g.w), a7);
        }
        // reduce across quarters
        a0 += __shfl_xor(a0, 16); a0 += __shfl_xor(a0, 32);
        a1 += __shfl_xor(a1, 16); a1 += __shfl_xor(a1, 32);
        a2 += __shfl_xor(a2, 16); a2 += __shfl_xor(a2, 32);
        a3 += __shfl_xor(a3, 16); a3 += __shfl_xor(a3, 32);
        a4 += __shfl_xor(a4, 16); a4 += __shfl_xor(a4, 32);
        a5 += __shfl_xor(a5, 16); a5 += __shfl_xor(a5, 32);
        a6 += __shfl_xor(a6, 16); a6 += __shfl_xor(a6, 32);
        a7 += __shfl_xor(a7, 16); a7 += __shfl_xor(a7, 32);
        if (q == 0) { // bias + ReLU + pack; swizzled slice write (2-way = free)
            a0 = fmaxf(a0 + bv0.x, 0.f); a1 = fmaxf(a1 + bv0.y, 0.f);
            a2 = fmaxf(a2 + bv0.z, 0.f); a3 = fmaxf(a3 + bv0.w, 0.f);
            a4 = fmaxf(a4 + bv1.x, 0.f); a5 = fmaxf(a5 + bv1.y, 0.f);
            a6 = fmaxf(a6 + bv1.z, 0.f); a7 = fmaxf(a7 + bv1.w, 0.f);
            uint4 o;
            o.x = (unsigned)(unsigned short)f2bf(a0) | ((unsigned)(unsigned short)f2bf(a1) << 16);
            o.y = (unsigned)(unsigned short)f2bf(a2) | ((unsigned)(unsigned short)f2bf(a3) << 16);
            o.z = (unsigned)(unsigned short)f2bf(a4) | ((unsigned)(unsigned short)f2bf(a5) << 16);
            o.w = (unsigned)(unsigned short)f2bf(a6) | ((unsigned)(unsigned short)f2bf(a7) << 16);
            ht[w][i][l16 ^ (i & 7)] = o;
        }
    }

    // W2 matmul: A = 16 h-rows (from LDS), B = WT2[48][128] -> m2b 16x48 (+16 zero cols)
    v4f acc[3];
#pragma unroll
    for (int t = 0; t < 3; t++) acc[t] = (v4f){0.f, 0.f, 0.f, 0.f};
#pragma unroll
    for (int kk = 0; kk < 4; kk++) {
        uint4 av = ht[w][l16][(kk * 4 + q) ^ (l16 & 7)];
        v8s af = *reinterpret_cast<const v8s*>(&av);
        const short* brow = WT2 + l16 * F_HID + q * 8 + kk * 32;
#pragma unroll
        for (int t = 0; t < 3; t++) {
            v8s bf = *reinterpret_cast<const v8s*>(brow + t * 16 * F_HID);
            acc[t] = __builtin_amdgcn_mfma_f32_16x16x32_bf16(af, bf, acc[t], 0, 0, 0);
        }
    }
#pragma unroll
    for (int r = 0; r < 4; r++) {
        int g = gBase + q * 4 + r;
        if (g < N_NODES) {
#pragma unroll
            for (int t = 0; t < 3; t++)
                m2b[(long)g * 64 + t * 16 + l16] = (unsigned short)f2bf(acc[t][r]);
            m2b[(long)g * 64 + 48 + l16] = 0;
        }
    }
}

// ---------------- layer-2 aggregation + bias + log_softmax ------------------
// Eighth-wave per edge, 2 gathers in flight in the main loop.

__global__ void k_agg2(const int2* __restrict__ rec, const int* __restrict__ rowptr,
                       const int* __restrict__ deg, const uint4* __restrict__ m2v,
                       const float* __restrict__ b2, float* __restrict__ out) {
    int node = blockIdx.x * 4 + (threadIdx.x >> 6);
    int lane = threadIdx.x & 63;
    if (node >= N_NODES) return;
    int start = rowptr[node], cnt = deg[node];
    int oc = lane >> 3, l8 = lane & 7;

    float a0 = 0.f, a1 = 0.f, a2 = 0.f, a3 = 0.f;
    float a4 = 0.f, a5 = 0.f, a6 = 0.f, a7 = 0.f;

    int e = start + oc;
    int n16 = cnt >> 4; // 16-edge batches: 2 gathers in flight
    for (int k = 0; k < n16; k++) {
        int2 r0 = rec[e];
        int2 r1 = rec[e + 8];
        uint4 g0 = m2v[(long)r0.x * 8 + l8];
        uint4 g1 = m2v[(long)r1.x * 8 + l8];
        float w0 = __int_as_float(r0.y), w1 = __int_as_float(r1.y);
        a0 = fmaf(w0, bflo(g0.x), a0); a1 = fmaf(w0, bfhi(g0.x), a1);
        a2 = fmaf(w0, bflo(g0.y), a2); a3 = fmaf(w0, bfhi(g0.y), a3);
        a4 = fmaf(w0, bflo(g0.z), a4); a5 = fmaf(w0, bfhi(g0.z), a5);
        a6 = fmaf(w0, bflo(g0.w), a6); a7 = fmaf(w0, bfhi(g0.w), a7);
        a0 = fmaf(w1, bflo(g1.x), a0); a1 = fmaf(w1, bfhi(g1.x), a1);
        a2 = fmaf(w1, bflo(g1.y), a2); a3 = fmaf(w1, bfhi(g1.y), a3);
        a4 = fmaf(w1, bflo(g1.z), a4); a5 = fmaf(w1, bfhi(g1.z), a5);
        a6 = fmaf(w1, bflo(g1.w), a6); a7 = fmaf(w1, bfhi(g1.w), a7);
        e += 16;
    }
    if (cnt & 8) {
        int2 r = rec[e];
        uint4 g = m2v[(long)r.x * 8 + l8];
        float w = __int_as_float(r.y);
        a0 = fmaf(w, bflo(g.x), a0); a1 = fmaf(w, bfhi(g.x), a1);
        a2 = fmaf(w, bflo(g.y), a2); a3 = fmaf(w, bfhi(g.y), a3);
        a4 = fmaf(w, bflo(g.z), a4); a5 = fmaf(w, bfhi(g.z), a5);
        a6 = fmaf(w, bflo(g.w), a6); a7 = fmaf(w, bfhi(g.w), a7);
        e += 8;
    }
    if (e < start + cnt) { // <8 leftover, oct-guarded
        int2 r = rec[e];
        uint4 g = m2v[(long)r.x * 8 + l8];
        float w = __int_as_float(r.y);
        a0 = fmaf(w, bflo(g.x), a0); a1 = fmaf(w, bfhi(g.x), a1);
        a2 = fmaf(w, bflo(g.y), a2); a3 = fmaf(w, bfhi(g.y), a3);
        a4 = fmaf(w, bflo(g.z), a4); a5 = fmaf(w, bfhi(g.z), a5);
        a6 = fmaf(w, bflo(g.w), a6); a7 = fmaf(w, bfhi(g.w), a7);
    }
    // reduce across octs: xor 8,16,32
#pragma unroll
    for (int off = 8; off < 64; off <<= 1) {
        a0 += __shfl_xor(a0, off); a1 += __shfl_xor(a1, off);
        a2 += __shfl_xor(a2, off); a3 += __shfl_xor(a3, off);
        a4 += __shfl_xor(a4, off); a5 += __shfl_xor(a5, off);
        a6 += __shfl_xor(a6, off); a7 += __shfl_xor(a7, off);
    }

    const float NEG = -3.4e38f;
    float v0 = NEG, v1 = NEG, v2 = NEG, v3 = NEG;
    float v4 = NEG, v5 = NEG, v6 = NEG, v7 = NEG;
    if (l8 < 5) { // feats 8*l8 .. +7 all < 40
        const float4* b4 = (const float4*)b2;
        float4 bv0 = b4[2 * l8], bv1 = b4[2 * l8 + 1];
        v0 = a0 + bv0.x; v1 = a1 + bv0.y; v2 = a2 + bv0.z; v3 = a3 + bv0.w;
        v4 = a4 + bv1.x; v5 = a5 + bv1.y; v6 = a6 + bv1.z; v7 = a7 + bv1.w;
    }
    float m = fmaxf(fmaxf(fmaxf(v0, v1), fmaxf(v2, v3)),
                    fmaxf(fmaxf(v4, v5), fmaxf(v6, v7)));
#pragma unroll
    for (int off = 1; off < 8; off <<= 1) m = fmaxf(m, __shfl_xor(m, off));
    float s = 0.f;
    if (l8 < 5)
        s = __expf(v0 - m) + __expf(v1 - m) + __expf(v2 - m) + __expf(v3 - m) +
            __expf(v4 - m) + __expf(v5 - m) + __expf(v6 - m) + __expf(v7 - m);
#pragma unroll
    for (int off = 1; off < 8; off <<= 1) s += __shfl_xor(s, off);
    if (oc == 0 && l8 < 5) {
        float ls = m + __logf(s);
        float4* op = (float4*)(out + (long)node * F_OUT);
        float4 o0, o1;
        o0.x = v0 - ls; o0.y = v1 - ls; o0.z = v2 - ls; o0.w = v3 - ls;
        o1.x = v4 - ls; o1.y = v5 - ls; o1.z = v6 - ls; o1.w = v7 - ls;
        op[2 * l8] = o0;
        op[2 * l8 + 1] = o1;
    }
}

// ---------------- launch ----------------

extern "C" void kernel_launch(void* const* d_in, const int* in_sizes, int n_in,
                              void* d_out, int out_size, void* d_ws, size_t ws_size,
                              hipStream_t stream) {
    const float* x  = (const float*)d_in[0];
    const int* ei   = (const int*)d_in[1]; // [2, E]: src then dst (int32)
    const int* src  = ei;
    const int* dst  = ei + N_EDGES;
    const float* ew = (const float*)d_in[2];
    const float* W1 = (const float*)d_in[3];
    const float* b1 = (const float*)d_in[4];
    const float* W2 = (const float*)d_in[5];
    const float* b2 = (const float*)d_in[6];
    float* out = (float*)d_out;

    char* ws = (char*)d_ws;
    size_t off = 0;
    auto alloc = [&](size_t bytes) {
        void* p = ws + off;
        off += (bytes + 255) & ~(size_t)255;
        return p;
    };
    unsigned short* m1b  = (unsigned short*)alloc((size_t)N_NODES * F_HID * 2); // 25.6 MB
    unsigned short* m2b  = (unsigned short*)alloc((size_t)N_NODES * 64 * 2);    // 12.8 MB
    int2*           rec  = (int2*)alloc((size_t)N_EDGES * 8);                   // 12.8 MB
    int*          rowptr = (int*)alloc((size_t)N_NODES * 4);
    int*          deg    = (int*)alloc((size_t)N_NODES * 4);
    int*          bCnt   = (int*)alloc(512 * 4);
    int*          bBase  = (int*)alloc(512 * 4);
    int*          bCur   = (int*)alloc(512 * 4);
    short*        WT1    = (short*)alloc((size_t)F_HID * F_IN * 2);
    short*        WT2    = (short*)alloc((size_t)F_OUT_PAD * F_HID * 2);

    // tmp (bucket-major edge records) aliases m2b: both 12.8 MB; tmp is dead
    // before k_ag writes m2b (order: bscatter -> fine consumes tmp -> ... -> ag).
    int2* tmp = (int2*)m2b;

    hipMemsetAsync(bCnt, 0, 512 * 4, stream);

    k_bhist<<<GB + CONVB, 512, 0, stream>>>(dst, bCnt, W1, WT1, W2, WT2);
    k_bscan<<<1, 512, 0, stream>>>(bCnt, bBase, bCur);
    k_bscatter<<<GB, 512, 0, stream>>>(src, dst, ew, bCur, tmp);
    k_fine<<<NB, 256, 0, stream>>>(tmp, bBase, rec, rowptr, deg);

    k_gemm1<<<(N_NODES + 63) / 64, 256, 0, stream>>>(x, WT1, m1b);
    k_ag<<<(N_NODES + 63) / 64, 256, 0, stream>>>(rec, rowptr, deg,
                                                  (const uint4*)m1b, b1, WT2, m2b);
    k_agg2<<<(N_NODES + 3) / 4, 256, 0, stream>>>(rec, rowptr, deg,
                                                  (const uint4*)m2b, b2, out);
}

// Round 5
// 483.975 us; speedup vs baseline: 1.0391x; 1.0146x over previous
//
#include <hip/hip_runtime.h>
#include <hip/hip_bf16.h>
#include <cstdint>

#define N_NODES 100000
#define N_EDGES 1600000
#define F_IN    512
#define F_HID   128
#define F_OUT   40
#define F_OUT_PAD 48

// bucketed CSR build params
#define BSH    8                       // 256 nodes per bucket
#define NB     391                     // ceil(100000/256)
#define BEPT   8                       // edges per thread (bucket kernels)
#define BCHUNK 4096                    // 512 thr * 8 edges per block
#define GB     391                     // ceil(E / BCHUNK)
#define CONVB  140                     // conv blocks appended to bhist grid
#define FCAP   6144                    // k_fine LDS record capacity (avg 4092, std 64)

typedef short v8s __attribute__((ext_vector_type(8)));
typedef float v4f __attribute__((ext_vector_type(4)));

__device__ __forceinline__ short f2bf(float f) {
    unsigned u = __float_as_uint(f);
    u += 0x7fffu + ((u >> 16) & 1u);
    return (short)(u >> 16);
}

__device__ __forceinline__ float bflo(unsigned u) { return __uint_as_float(u << 16); }
__device__ __forceinline__ float bfhi(unsigned u) { return __uint_as_float(u & 0xffff0000u); }

__device__ __forceinline__ v8s pack8(float4 a, float4 b) {
    v8s r;
    r[0] = f2bf(a.x); r[1] = f2bf(a.y); r[2] = f2bf(a.z); r[3] = f2bf(a.w);
    r[4] = f2bf(b.x); r[5] = f2bf(b.y); r[6] = f2bf(b.z); r[7] = f2bf(b.w);
    return r;
}

// async 16B global->LDS (direct-to-shared DMA; LDS dest = wave-uniform base + lane*16)
__device__ __forceinline__ void gload16(const void* g, void* l) {
    __builtin_amdgcn_global_load_lds(
        (const __attribute__((address_space(1))) void*)g,
        (__attribute__((address_space(3))) void*)l, 16, 0, 0);
}

// ---------------- bucketed CSR build ----------------

// A: bucket histogram (LDS-aggregated) + weight convert (independent blocks)
__global__ __launch_bounds__(512) void k_bhist(const int* __restrict__ dst,
                                               int* __restrict__ bcnt,
                                               const float* __restrict__ W1,
                                               short* __restrict__ WT1,
                                               const float* __restrict__ W2,
                                               short* __restrict__ WT2) {
    if (blockIdx.x >= GB) { // weight transpose+convert tail blocks
        int i = (blockIdx.x - GB) * 512 + threadIdx.x;
        if (i < F_IN * F_HID) {            // i = n*512 + k
            int n = i >> 9, k = i & 511;
            WT1[i] = f2bf(W1[k * F_HID + n]);
        } else {
            int j = i - F_IN * F_HID;      // j = n*128 + k
            if (j < F_OUT_PAD * F_HID) {
                int n = j >> 7, k = j & 127;
                WT2[j] = (n < F_OUT) ? f2bf(W2[k * F_OUT + n]) : (short)0;
            }
        }
        return;
    }
    __shared__ int lh[512];
    int tid = threadIdx.x;
    lh[tid] = 0;
    __syncthreads();
    long e0 = (long)blockIdx.x * BCHUNK;
#pragma unroll
    for (int i = 0; i < BEPT; i++) {
        long e = e0 + tid + i * 512;
        if (e < N_EDGES) atomicAdd(&lh[dst[e] >> BSH], 1);
    }
    __syncthreads();
    if (tid < NB && lh[tid]) atomicAdd(&bcnt[tid], lh[tid]);
}

// scan bucket counts -> bucket bases; seed bucket cursors
__global__ __launch_bounds__(512) void k_bscan(const int* __restrict__ bcnt,
                                               int* __restrict__ bbase,
                                               int* __restrict__ bcur) {
    __shared__ int sm[512];
    int tid = threadIdx.x;
    int v = (tid < NB) ? bcnt[tid] : 0;
    sm[tid] = v;
    __syncthreads();
    for (int off = 1; off < 512; off <<= 1) {
        int t = (tid >= off) ? sm[tid - off] : 0;
        __syncthreads();
        sm[tid] += t;
        __syncthreads();
    }
    if (tid < NB) {
        int ex = sm[tid] - v;
        bbase[tid] = ex;
        bcur[tid] = ex;
    }
    if (tid == 511) bbase[NB] = sm[511];
}

// B: reorder edges into bucket-major tmp.
// tmp record: (src | dstLow<<17, w_bits)  [src<2^17, dstLow<2^8]
__global__ __launch_bounds__(512) void k_bscatter(const int* __restrict__ src,
                                                  const int* __restrict__ dst,
                                                  const float* __restrict__ w,
                                                  int* __restrict__ bcur,
                                                  int2* __restrict__ tmp) {
    __shared__ int cntA[512];
    __shared__ int ofsA[512];
    __shared__ int lcur[512];
    __shared__ int gb[512];
    __shared__ __align__(16) int2 recBuf[BCHUNK];
    __shared__ unsigned short bkt[BCHUNK];
    int tid = threadIdx.x;
    long e0 = (long)blockIdx.x * BCHUNK;
    cntA[tid] = 0;
    __syncthreads();

    int dloc[BEPT];
#pragma unroll
    for (int i = 0; i < BEPT; i++) {
        long e = e0 + tid + i * 512;
        int d = (e < N_EDGES) ? dst[e] : -1;
        dloc[i] = d;
        if (d >= 0) atomicAdd(&cntA[d >> BSH], 1);
    }
    __syncthreads();

    int v = cntA[tid];
    ofsA[tid] = v;
    __syncthreads();
    for (int off = 1; off < 512; off <<= 1) {
        int t = (tid >= off) ? ofsA[tid - off] : 0;
        __syncthreads();
        ofsA[tid] += t;
        __syncthreads();
    }
    int excl = ofsA[tid] - v;
    ofsA[tid] = excl;
    lcur[tid] = excl;
    if (tid < NB && v > 0) gb[tid] = atomicAdd(&bcur[tid], v);
    __syncthreads();

#pragma unroll
    for (int i = 0; i < BEPT; i++) {
        int d = dloc[i];
        if (d >= 0) {
            long e = e0 + tid + i * 512;
            int j = d >> BSH;
            int slot = atomicAdd(&lcur[j], 1);
            recBuf[slot] = make_int2(src[e] | ((d & 255) << 17), __float_as_int(w[e]));
            bkt[slot] = (unsigned short)j;
        }
    }
    __syncthreads();

    long rem = N_EDGES - e0;
    int total = (rem < BCHUNK) ? (int)rem : BCHUNK;
    for (int s = tid; s < total; s += 512) {
        int j = bkt[s];
        tmp[gb[j] + (s - ofsA[j])] = recBuf[s];
    }
}

// C: per-bucket fine sort by node; emits packed rd = {rowptr, deg} and
// writes rec coalesced.
__global__ __launch_bounds__(256) void k_fine(const int2* __restrict__ tmp,
                                              const int* __restrict__ bbase,
                                              int2* __restrict__ rec,
                                              int2* __restrict__ rd) {
    __shared__ int hist[256];
    __shared__ int ofs[256];
    __shared__ int cur[256];
    __shared__ __align__(16) int2 recOut[FCAP];
    int tid = threadIdx.x, b = blockIdx.x;
    int base = bbase[b];
    int cnt = bbase[b + 1] - base;

    hist[tid] = 0;
    __syncthreads();
    for (int i = tid; i < cnt; i += 256) {
        unsigned u = (unsigned)tmp[base + i].x;
        atomicAdd(&hist[u >> 17], 1);
    }
    __syncthreads();

    int v = hist[tid];
    ofs[tid] = v;
    __syncthreads();
    for (int off = 1; off < 256; off <<= 1) {
        int t = (tid >= off) ? ofs[tid - off] : 0;
        __syncthreads();
        ofs[tid] += t;
        __syncthreads();
    }
    int excl = ofs[tid] - v;
    ofs[tid] = excl;
    cur[tid] = excl;
    int node = (b << BSH) + tid;
    if (node < N_NODES) rd[node] = make_int2(base + excl, v);
    __syncthreads();

    if (cnt <= FCAP) {
        for (int i = tid; i < cnt; i += 256) {
            int2 r = tmp[base + i];
            unsigned u = (unsigned)r.x;
            int slot = atomicAdd(&cur[u >> 17], 1);
            recOut[slot] = make_int2((int)(u & 0x1FFFFu), r.y);
        }
        __syncthreads();
        for (int i = tid; i < cnt; i += 256) rec[base + i] = recOut[i];
    } else { // statistically unreachable overflow fallback (still correct)
        for (int i = tid; i < cnt; i += 256) {
            int2 r = tmp[base + i];
            unsigned u = (unsigned)r.x;
            int slot = atomicAdd(&cur[u >> 17], 1);
            rec[base + slot] = make_int2((int)(u & 0x1FFFFu), r.y);
        }
    }
}

// ---------------- GEMM1 (LDS-staged): m1b = x @ W1 ----------------

__global__ __launch_bounds__(256) void k_gemm1(const float* __restrict__ x,
                                               const short* __restrict__ WT1,
                                               unsigned short* __restrict__ m1b) {
    __shared__ __align__(16) float aBuf[2][64 * 32];  // 2 x 8 KB
    __shared__ __align__(16) short bBuf[2][128 * 32]; // 2 x 8 KB
    int tid = threadIdx.x, w = tid >> 6, lane = tid & 63;
    int quad = lane >> 4, l16 = lane & 15;
    long rowBase = (long)blockIdx.x * 64;

    int ar = lane >> 3, ac = lane & 7; // A: 8 rows x 8 kblocks(16B=4 floats)
    int br = lane >> 2, bc = lane & 3; // B: 16 rows x 4 kblocks(16B=8 bf16)

    v4f acc[8];
#pragma unroll
    for (int t = 0; t < 8; t++) acc[t] = (v4f){0.f, 0.f, 0.f, 0.f};

    auto stage = [&](int kc, int buf) {
#pragma unroll
        for (int i = 0; i < 2; i++) {
            int rl = w * 16 + i * 8 + ar;
            long rg = rowBase + rl;
            if (rg > N_NODES - 1) rg = N_NODES - 1;
            const float* gp = x + rg * F_IN + kc * 32 + ((ac ^ (rl & 7)) << 2);
            gload16(gp, &aBuf[buf][(w * 16 + i * 8) * 32]);
        }
#pragma unroll
        for (int i = 0; i < 2; i++) {
            int n = w * 32 + i * 16 + br;
            const short* gp = WT1 + n * F_IN + kc * 32 + ((bc ^ ((n >> 1) & 3)) << 3);
            gload16(gp, &bBuf[buf][(w * 32 + i * 16) * 32]);
        }
    };

    stage(0, 0);
#pragma unroll
    for (int kc = 0; kc < 16; kc++) {
        __syncthreads();
        int buf = kc & 1;
        if (kc < 15) stage(kc + 1, buf ^ 1);
        int arow = w * 16 + l16;
        int p0 = (2 * quad) ^ (l16 & 7);
        float4 av0 = *(const float4*)&aBuf[buf][arow * 32 + p0 * 4];
        float4 av1 = *(const float4*)&aBuf[buf][arow * 32 + (p0 ^ 1) * 4];
        v8s af = pack8(av0, av1);
#pragma unroll
        for (int t = 0; t < 8; t++) {
            int n = t * 16 + l16;
            int p = quad ^ ((n >> 1) & 3);
            v8s bf = *(const v8s*)&bBuf[buf][n * 32 + p * 8];
            acc[t] = __builtin_amdgcn_mfma_f32_16x16x32_bf16(af, bf, acc[t], 0, 0, 0);
        }
    }

#pragma unroll
    for (int t = 0; t < 8; t++)
#pragma unroll
        for (int r = 0; r < 4; r++) {
            long row = rowBase + w * 16 + quad * 4 + r;
            if (row < N_NODES)
                m1b[row * F_HID + t * 16 + l16] = (unsigned short)f2bf(acc[t][r]);
        }
}

// ---------------- FUSED layer-1 aggregation + ReLU + GEMM2 ------------------
// v2: WAVE-PER-NODE (spatial node parallelism). 512-thr block = 8 waves;
// each wave aggregates 2 nodes (serially), so all 8 waves' gathers are in
// flight concurrently -- no per-node pipeline drain across the block's 16
// nodes. Quarter-wave per edge (16 lanes x 16 B), 4 gathers in flight.
// h rows -> padded LDS tile [16][17] (2-way conflicts = free); wave 0 then
// applies W2 with 12 MFMAs and writes m2b (h never hits HBM).

__global__ __launch_bounds__(512) void k_ag(const int2* __restrict__ rec,
                                            const int2* __restrict__ rd,
                                            const uint4* __restrict__ m1v,
                                            const float* __restrict__ b1,
                                            const short* __restrict__ WT2,
                                            unsigned short* __restrict__ m2b) {
    __shared__ uint4 ht[16][17]; // padded: MFMA-read 2-way only
    int tid = threadIdx.x, w = tid >> 6, lane = tid & 63;
    int q = lane >> 4, l16 = lane & 15;
    int gBase = blockIdx.x * 16;

    const float4* b4 = (const float4*)b1;
    float4 bv0 = b4[2 * l16], bv1 = b4[2 * l16 + 1];

#pragma unroll
    for (int half = 0; half < 2; half++) {
        int node = gBase + half * 8 + w;
        int2 sd = make_int2(0, 0);
        if (node < N_NODES) sd = rd[node];
        int start = sd.x, cnt = sd.y;

        float a0 = 0.f, a1 = 0.f, a2 = 0.f, a3 = 0.f;
        float a4 = 0.f, a5 = 0.f, a6 = 0.f, a7 = 0.f;
        int e = start + q;
        int n16 = cnt >> 4; // 16-edge batches: 4 gathers in flight
        for (int k = 0; k < n16; k++) {
            int2 r0 = rec[e];
            int2 r1 = rec[e + 4];
            int2 r2 = rec[e + 8];
            int2 r3 = rec[e + 12];
            uint4 g0 = m1v[(long)r0.x * 16 + l16];
            uint4 g1 = m1v[(long)r1.x * 16 + l16];
            uint4 g2 = m1v[(long)r2.x * 16 + l16];
            uint4 g3 = m1v[(long)r3.x * 16 + l16];
            float w0 = __int_as_float(r0.y), w1 = __int_as_float(r1.y);
            float w2 = __int_as_float(r2.y), w3 = __int_as_float(r3.y);
            a0 = fmaf(w0, bflo(g0.x), a0); a1 = fmaf(w0, bfhi(g0.x), a1);
            a2 = fmaf(w0, bflo(g0.y), a2); a3 = fmaf(w0, bfhi(g0.y), a3);
            a4 = fmaf(w0, bflo(g0.z), a4); a5 = fmaf(w0, bfhi(g0.z), a5);
            a6 = fmaf(w0, bflo(g0.w), a6); a7 = fmaf(w0, bfhi(g0.w), a7);
            a0 = fmaf(w1, bflo(g1.x), a0); a1 = fmaf(w1, bfhi(g1.x), a1);
            a2 = fmaf(w1, bflo(g1.y), a2); a3 = fmaf(w1, bfhi(g1.y), a3);
            a4 = fmaf(w1, bflo(g1.z), a4); a5 = fmaf(w1, bfhi(g1.z), a5);
            a6 = fmaf(w1, bflo(g1.w), a6); a7 = fmaf(w1, bfhi(g1.w), a7);
            a0 = fmaf(w2, bflo(g2.x), a0); a1 = fmaf(w2, bfhi(g2.x), a1);
            a2 = fmaf(w2, bflo(g2.y), a2); a3 = fmaf(w2, bfhi(g2.y), a3);
            a4 = fmaf(w2, bflo(g2.z), a4); a5 = fmaf(w2, bfhi(g2.z), a5);
            a6 = fmaf(w2, bflo(g2.w), a6); a7 = fmaf(w2, bfhi(g2.w), a7);
            a0 = fmaf(w3, bflo(g3.x), a0); a1 = fmaf(w3, bfhi(g3.x), a1);
            a2 = fmaf(w3, bflo(g3.y), a2); a3 = fmaf(w3, bfhi(g3.y), a3);
            a4 = fmaf(w3, bflo(g3.z), a4); a5 = fmaf(w3, bfhi(g3.z), a5);
            a6 = fmaf(w3, bflo(g3.w), a6); a7 = fmaf(w3, bfhi(g3.w), a7);
            e += 16;
        }
        if (cnt & 8) { // 8-edge batch: 2 gathers in flight
            int2 r0 = rec[e];
            int2 r1 = rec[e + 4];
            uint4 g0 = m1v[(long)r0.x * 16 + l16];
            uint4 g1 = m1v[(long)r1.x * 16 + l16];
            float w0 = __int_as_float(r0.y), w1 = __int_as_float(r1.y);
            a0 = fmaf(w0, bflo(g0.x), a0); a1 = fmaf(w0, bfhi(g0.x), a1);
            a2 = fmaf(w0, bflo(g0.y), a2); a3 = fmaf(w0, bfhi(g0.y), a3);
            a4 = fmaf(w0, bflo(g0.z), a4); a5 = fmaf(w0, bfhi(g0.z), a5);
            a6 = fmaf(w0, bflo(g0.w), a6); a7 = fmaf(w0, bfhi(g0.w), a7);
            a0 = fmaf(w1, bflo(g1.x), a0); a1 = fmaf(w1, bfhi(g1.x), a1);
            a2 = fmaf(w1, bflo(g1.y), a2); a3 = fmaf(w1, bfhi(g1.y), a3);
            a4 = fmaf(w1, bflo(g1.z), a4); a5 = fmaf(w1, bfhi(g1.z), a5);
            a6 = fmaf(w1, bflo(g1.w), a6); a7 = fmaf(w1, bfhi(g1.w), a7);
            e += 8;
        }
        for (int t = e; t < start + cnt; t += 4) { // <8 leftover, quarter-strided
            int2 r = rec[t];
            uint4 g = m1v[(long)r.x * 16 + l16];
            float ww = __int_as_float(r.y);
            a0 = fmaf(ww, bflo(g.x), a0); a1 = fmaf(ww, bfhi(g.x), a1);
            a2 = fmaf(ww, bflo(g.y), a2); a3 = fmaf(ww, bfhi(g.y), a3);
            a4 = fmaf(ww, bflo(g.z), a4); a5 = fmaf(ww, bfhi(g.z), a5);
            a6 = fmaf(ww, bflo(g.w), a6); a7 = fmaf(ww, bfhi(g.w), a7);
        }
        // reduce across quarters
        a0 += __shfl_xor(a0, 16); a0 += __shfl_xor(a0, 32);
        a1 += __shfl_xor(a1, 16); a1 += __shfl_xor(a1, 32);
        a2 += __shfl_xor(a2, 16); a2 += __shfl_xor(a2, 32);
        a3 += __shfl_xor(a3, 16); a3 += __shfl_xor(a3, 32);
        a4 += __shfl_xor(a4, 16); a4 += __shfl_xor(a4, 32);
        a5 += __shfl_xor(a5, 16); a5 += __shfl_xor(a5, 32);
        a6 += __shfl_xor(a6, 16); a6 += __shfl_xor(a6, 32);
        a7 += __shfl_xor(a7, 16); a7 += __shfl_xor(a7, 32);
        if (q == 0) { // bias + ReLU + pack
            a0 = fmaxf(a0 + bv0.x, 0.f); a1 = fmaxf(a1 + bv0.y, 0.f);
            a2 = fmaxf(a2 + bv0.z, 0.f); a3 = fmaxf(a3 + bv0.w, 0.f);
            a4 = fmaxf(a4 + bv1.x, 0.f); a5 = fmaxf(a5 + bv1.y, 0.f);
            a6 = fmaxf(a6 + bv1.z, 0.f); a7 = fmaxf(a7 + bv1.w, 0.f);
            uint4 o;
            o.x = (unsigned)(unsigned short)f2bf(a0) | ((unsigned)(unsigned short)f2bf(a1) << 16);
            o.y = (unsigned)(unsigned short)f2bf(a2) | ((unsigned)(unsigned short)f2bf(a3) << 16);
            o.z = (unsigned)(unsigned short)f2bf(a4) | ((unsigned)(unsigned short)f2bf(a5) << 16);
            o.w = (unsigned)(unsigned short)f2bf(a6) | ((unsigned)(unsigned short)f2bf(a7) << 16);
            ht[half * 8 + w][l16] = o;
        }
    }
    __syncthreads();

    if (w == 0) {
        // W2 matmul: A = 16 h-rows (LDS), B = WT2[48][128] -> m2b 16x48 (+16 zero)
        v4f acc[3];
#pragma unroll
        for (int t = 0; t < 3; t++) acc[t] = (v4f){0.f, 0.f, 0.f, 0.f};
#pragma unroll
        for (int kk = 0; kk < 4; kk++) {
            uint4 av = ht[l16][kk * 4 + q];
            v8s af = *reinterpret_cast<const v8s*>(&av);
            const short* brow = WT2 + l16 * F_HID + q * 8 + kk * 32;
#pragma unroll
            for (int t = 0; t < 3; t++) {
                v8s bf = *reinterpret_cast<const v8s*>(brow + t * 16 * F_HID);
                acc[t] = __builtin_amdgcn_mfma_f32_16x16x32_bf16(af, bf, acc[t], 0, 0, 0);
            }
        }
#pragma unroll
        for (int r = 0; r < 4; r++) {
            int g = gBase + q * 4 + r;
            if (g < N_NODES) {
#pragma unroll
                for (int t = 0; t < 3; t++)
                    m2b[(long)g * 64 + t * 16 + l16] = (unsigned short)f2bf(acc[t][r]);
                m2b[(long)g * 64 + 48 + l16] = 0;
            }
        }
    }
}

// ---------------- layer-2 aggregation + bias + log_softmax ------------------
// Eighth-wave per edge, 2 gathers in flight in the main loop.

__global__ void k_agg2(const int2* __restrict__ rec, const int2* __restrict__ rd,
                       const uint4* __restrict__ m2v, const float* __restrict__ b2,
                       float* __restrict__ out) {
    int node = blockIdx.x * 4 + (threadIdx.x >> 6);
    int lane = threadIdx.x & 63;
    if (node >= N_NODES) return;
    int2 sd = rd[node];
    int start = sd.x, cnt = sd.y;
    int oc = lane >> 3, l8 = lane & 7;

    float a0 = 0.f, a1 = 0.f, a2 = 0.f, a3 = 0.f;
    float a4 = 0.f, a5 = 0.f, a6 = 0.f, a7 = 0.f;

    int e = start + oc;
    int n16 = cnt >> 4; // 16-edge batches: 2 gathers in flight
    for (int k = 0; k < n16; k++) {
        int2 r0 = rec[e];
        int2 r1 = rec[e + 8];
        uint4 g0 = m2v[(long)r0.x * 8 + l8];
        uint4 g1 = m2v[(long)r1.x * 8 + l8];
        float w0 = __int_as_float(r0.y), w1 = __int_as_float(r1.y);
        a0 = fmaf(w0, bflo(g0.x), a0); a1 = fmaf(w0, bfhi(g0.x), a1);
        a2 = fmaf(w0, bflo(g0.y), a2); a3 = fmaf(w0, bfhi(g0.y), a3);
        a4 = fmaf(w0, bflo(g0.z), a4); a5 = fmaf(w0, bfhi(g0.z), a5);
        a6 = fmaf(w0, bflo(g0.w), a6); a7 = fmaf(w0, bfhi(g0.w), a7);
        a0 = fmaf(w1, bflo(g1.x), a0); a1 = fmaf(w1, bfhi(g1.x), a1);
        a2 = fmaf(w1, bflo(g1.y), a2); a3 = fmaf(w1, bfhi(g1.y), a3);
        a4 = fmaf(w1, bflo(g1.z), a4); a5 = fmaf(w1, bfhi(g1.z), a5);
        a6 = fmaf(w1, bflo(g1.w), a6); a7 = fmaf(w1, bfhi(g1.w), a7);
        e += 16;
    }
    if (cnt & 8) {
        int2 r = rec[e];
        uint4 g = m2v[(long)r.x * 8 + l8];
        float w = __int_as_float(r.y);
        a0 = fmaf(w, bflo(g.x), a0); a1 = fmaf(w, bfhi(g.x), a1);
        a2 = fmaf(w, bflo(g.y), a2); a3 = fmaf(w, bfhi(g.y), a3);
        a4 = fmaf(w, bflo(g.z), a4); a5 = fmaf(w, bfhi(g.z), a5);
        a6 = fmaf(w, bflo(g.w), a6); a7 = fmaf(w, bfhi(g.w), a7);
        e += 8;
    }
    if (e < start + cnt) { // <8 leftover, oct-guarded
        int2 r = rec[e];
        uint4 g = m2v[(long)r.x * 8 + l8];
        float w = __int_as_float(r.y);
        a0 = fmaf(w, bflo(g.x), a0); a1 = fmaf(w, bfhi(g.x), a1);
        a2 = fmaf(w, bflo(g.y), a2); a3 = fmaf(w, bfhi(g.y), a3);
        a4 = fmaf(w, bflo(g.z), a4); a5 = fmaf(w, bfhi(g.z), a5);
        a6 = fmaf(w, bflo(g.w), a6); a7 = fmaf(w, bfhi(g.w), a7);
    }
    // reduce across octs: xor 8,16,32
#pragma unroll
    for (int off = 8; off < 64; off <<= 1) {
        a0 += __shfl_xor(a0, off); a1 += __shfl_xor(a1, off);
        a2 += __shfl_xor(a2, off); a3 += __shfl_xor(a3, off);
        a4 += __shfl_xor(a4, off); a5 += __shfl_xor(a5, off);
        a6 += __shfl_xor(a6, off); a7 += __shfl_xor(a7, off);
    }

    const float NEG = -3.4e38f;
    float v0 = NEG, v1 = NEG, v2 = NEG, v3 = NEG;
    float v4 = NEG, v5 = NEG, v6 = NEG, v7 = NEG;
    if (l8 < 5) { // feats 8*l8 .. +7 all < 40
        const float4* b4 = (const float4*)b2;
        float4 bv0 = b4[2 * l8], bv1 = b4[2 * l8 + 1];
        v0 = a0 + bv0.x; v1 = a1 + bv0.y; v2 = a2 + bv0.z; v3 = a3 + bv0.w;
        v4 = a4 + bv1.x; v5 = a5 + bv1.y; v6 = a6 + bv1.z; v7 = a7 + bv1.w;
    }
    float m = fmaxf(fmaxf(fmaxf(v0, v1), fmaxf(v2, v3)),
                    fmaxf(fmaxf(v4, v5), fmaxf(v6, v7)));
#pragma unroll
    for (int off = 1; off < 8; off <<= 1) m = fmaxf(m, __shfl_xor(m, off));
    float s = 0.f;
    if (l8 < 5)
        s = __expf(v0 - m) + __expf(v1 - m) + __expf(v2 - m) + __expf(v3 - m) +
            __expf(v4 - m) + __expf(v5 - m) + __expf(v6 - m) + __expf(v7 - m);
#pragma unroll
    for (int off = 1; off < 8; off <<= 1) s += __shfl_xor(s, off);
    if (oc == 0 && l8 < 5) {
        float ls = m + __logf(s);
        float4* op = (float4*)(out + (long)node * F_OUT);
        float4 o0, o1;
        o0.x = v0 - ls; o0.y = v1 - ls; o0.z = v2 - ls; o0.w = v3 - ls;
        o1.x = v4 - ls; o1.y = v5 - ls; o1.z = v6 - ls; o1.w = v7 - ls;
        op[2 * l8] = o0;
        op[2 * l8 + 1] = o1;
    }
}

// ---------------- launch ----------------

extern "C" void kernel_launch(void* const* d_in, const int* in_sizes, int n_in,
                              void* d_out, int out_size, void* d_ws, size_t ws_size,
                              hipStream_t stream) {
    const float* x  = (const float*)d_in[0];
    const int* ei   = (const int*)d_in[1]; // [2, E]: src then dst (int32)
    const int* src  = ei;
    const int* dst  = ei + N_EDGES;
    const float* ew = (const float*)d_in[2];
    const float* W1 = (const float*)d_in[3];
    const float* b1 = (const float*)d_in[4];
    const float* W2 = (const float*)d_in[5];
    const float* b2 = (const float*)d_in[6];
    float* out = (float*)d_out;

    char* ws = (char*)d_ws;
    size_t off = 0;
    auto alloc = [&](size_t bytes) {
        void* p = ws + off;
        off += (bytes + 255) & ~(size_t)255;
        return p;
    };
    unsigned short* m1b  = (unsigned short*)alloc((size_t)N_NODES * F_HID * 2); // 25.6 MB
    unsigned short* m2b  = (unsigned short*)alloc((size_t)N_NODES * 64 * 2);    // 12.8 MB
    int2*           rec  = (int2*)alloc((size_t)N_EDGES * 8);                   // 12.8 MB
    int2*           rd   = (int2*)alloc((size_t)N_NODES * 8);                   // 0.8 MB
    int*          bCnt   = (int*)alloc(512 * 4);
    int*          bBase  = (int*)alloc(512 * 4);
    int*          bCur   = (int*)alloc(512 * 4);
    short*        WT1    = (short*)alloc((size_t)F_HID * F_IN * 2);
    short*        WT2    = (short*)alloc((size_t)F_OUT_PAD * F_HID * 2);

    // tmp (bucket-major edge records) aliases m2b: both 12.8 MB; tmp is dead
    // before k_ag writes m2b (order: bscatter -> fine consumes tmp -> ... -> ag).
    int2* tmp = (int2*)m2b;

    hipMemsetAsync(bCnt, 0, 512 * 4, stream);

    k_bhist<<<GB + CONVB, 512, 0, stream>>>(dst, bCnt, W1, WT1, W2, WT2);
    k_bscan<<<1, 512, 0, stream>>>(bCnt, bBase, bCur);
    k_bscatter<<<GB, 512, 0, stream>>>(src, dst, ew, bCur, tmp);
    k_fine<<<NB, 256, 0, stream>>>(tmp, bBase, rec, rd);

    k_gemm1<<<(N_NODES + 63) / 64, 256, 0, stream>>>(x, WT1, m1b);
    k_ag<<<(N_NODES + 15) / 16, 512, 0, stream>>>(rec, rd, (const uint4*)m1b,
                                                  b1, WT2, m2b);
    k_agg2<<<(N_NODES + 3) / 4, 256, 0, stream>>>(rec, rd, (const uint4*)m2b,
                                                  b2, out);
}